// Round 6
// baseline (201.901 us; speedup 1.0000x reference)
//
#include <hip/hip_runtime.h>
#include <hip/hip_bf16.h>
#include <stdint.h>

#define NROWS 8192
#define NDIM  512
#define MARGIN 0.3f
// 128 tile-rows of 64; upper triangle = 8256 tiles, grouped in 16x16 supertiles
#define NT 8256

typedef __attribute__((ext_vector_type(4))) float floatx4;
typedef __attribute__((ext_vector_type(8))) short shortx8;

__device__ inline unsigned short f32_to_bf16_bits(float x) {
  union { float f; unsigned int u; } v; v.f = x;
  unsigned int r = v.u + 0x7FFFu + ((v.u >> 16) & 1u);  // RNE
  return (unsigned short)(r >> 16);
}

// fp32 -> bf16, 16 floats per thread; zeroes the (poisoned) output scalar
__global__ void convert_kernel(const float4* __restrict__ in, shortx8* __restrict__ out,
                               float* __restrict__ loss_out) {
  int i = blockIdx.x * blockDim.x + threadIdx.x;
  if (i == 0) loss_out[0] = 0.f;
  float4 f[4];
#pragma unroll
  for (int j = 0; j < 4; j++) f[j] = in[i * 4 + j];
  shortx8 o0, o1;
#pragma unroll
  for (int j = 0; j < 2; j++) {
    o0[j*4+0] = (short)f32_to_bf16_bits(f[j].x);
    o0[j*4+1] = (short)f32_to_bf16_bits(f[j].y);
    o0[j*4+2] = (short)f32_to_bf16_bits(f[j].z);
    o0[j*4+3] = (short)f32_to_bf16_bits(f[j].w);
    o1[j*4+0] = (short)f32_to_bf16_bits(f[j+2].x);
    o1[j*4+1] = (short)f32_to_bf16_bits(f[j+2].y);
    o1[j*4+2] = (short)f32_to_bf16_bits(f[j+2].z);
    o1[j*4+3] = (short)f32_to_bf16_bits(f[j+2].w);
  }
  out[i * 2 + 0] = o0;
  out[i * 2 + 1] = o1;
}

__device__ inline void gload_lds16(const void* g, void* l) {
  __builtin_amdgcn_global_load_lds(
      (const __attribute__((address_space(1))) unsigned int*)g,
      (__attribute__((address_space(3))) unsigned int*)l, 16, 0, 0);
}

// Barrier-free GEMM: one wave per 64x64 upper-tri tile of sim = X·X^T.
// Wave-private double-buffered LDS (16 KB/block -> 10 blocks/CU). No
// __syncthreads anywhere: the LDS-DMA -> ds_read hazard is ordered by an
// EXPLICIT `s_waitcnt vmcnt(8)` (asm volatile + memory clobber) — R5 showed
// the compiler emits no wave-level wait for this hazard on its own (NaN race).
// Prefetch for tile kt+1 is issued BEFORE the wait, so 8 loads stay in flight
// across every iteration (AITER-style, never vmcnt(0) mid-loop).
__launch_bounds__(64, 4)
__global__ void loss_kernel(const ushort* __restrict__ Xb, const int* __restrict__ tg,
                            float* __restrict__ out) {
  __shared__ ushort As[2][2048];   // 64 rows x 32 k, double-buffered (8 KB)
  __shared__ ushort Bs[2][2048];   // 8 KB

  // supertile decode: 8 diagonal supers (136 tiles, inner upper-tri) then
  // 28 off-diagonal supers (256 tiles, row-major 16x16)
  int t = blockIdx.x;
  int ti, tj;
  if (t < 1088) {
    int si = t / 136;
    int q  = t - si * 136;
    int ii = 0;
    while (q >= 16 - ii) { q -= 16 - ii; ii++; }
    ti = si * 16 + ii;
    tj = si * 16 + ii + q;
  } else {
    int q = t - 1088;
    int s = q >> 8, r = q & 255;
    int si = 0;
    while (s >= 7 - si) { s -= 7 - si; si++; }
    int sj = si + 1 + s;
    ti = si * 16 + (r >> 4);
    tj = sj * 16 + (r & 15);
  }

  const int lane = threadIdx.x & 63;
  const int quad = lane >> 4;
  const int l16  = lane & 15;

  const int rowBase = ti * 64;
  const int colBase = tj * 64;

  // Staging: 64x32 tile = 4 chunks of 1 KB (16 rows). DMA puts lane's 16 B at
  // chunkBase + lane*16; we fetch global (r_t = ch*16 + lane/4,
  // slot = (lane&3) ^ ((r_t>>1)&3)) so LDS holds a swizzled layout; the read
  // side un-swizzles. 2-way bank aliasing max (free on wave64).
  const int srt = lane >> 2;            // row within chunk
  const int sp  = lane & 3;             // physical 16B slot

  unsigned ga[4], gb[4];
#pragma unroll
  for (int ch = 0; ch < 4; ch++) {
    int r_t  = ch * 16 + srt;
    int slot = sp ^ ((r_t >> 1) & 3);
    ga[ch] = (unsigned)((rowBase + r_t) * NDIM + slot * 8);
    gb[ch] = (unsigned)((colBase + r_t) * NDIM + slot * 8);
  }

#define STAGE(KT, BUF)                                                  \
  do {                                                                  \
    _Pragma("unroll")                                                   \
    for (int ch = 0; ch < 4; ch++) {                                    \
      gload_lds16(Xb + ga[ch] + (KT) * 32, &As[BUF][ch * 512]);         \
      gload_lds16(Xb + gb[ch] + (KT) * 32, &Bs[BUF][ch * 512]);         \
    }                                                                   \
  } while (0)

  floatx4 acc[4][4];
#pragma unroll
  for (int a = 0; a < 4; a++)
#pragma unroll
    for (int b = 0; b < 4; b++) acc[a][b] = (floatx4)(0.f);

  STAGE(0, 0);

#pragma unroll
  for (int kt = 0; kt < 16; kt++) {
    const int buf = kt & 1;
    if (kt < 15) {
      STAGE(kt + 1, buf ^ 1);                       // 8 loads in flight...
      asm volatile("s_waitcnt vmcnt(8)" ::: "memory");  // ...tile kt landed
    } else {
      asm volatile("s_waitcnt vmcnt(0)" ::: "memory");
    }

    shortx8 a[4], b[4];
#pragma unroll
    for (int mt = 0; mt < 4; mt++) {
      const int row = mt * 16 + l16;
      const int phys = quad ^ ((row >> 1) & 3);
      a[mt] = *(const shortx8*)(&As[buf][row * 32 + phys * 8]);
    }
#pragma unroll
    for (int nt = 0; nt < 4; nt++) {
      const int row = nt * 16 + l16;
      const int phys = quad ^ ((row >> 1) & 3);
      b[nt] = *(const shortx8*)(&Bs[buf][row * 32 + phys * 8]);
    }
#pragma unroll
    for (int mt = 0; mt < 4; mt++)
#pragma unroll
      for (int nt = 0; nt < 4; nt++)
        acc[mt][nt] = __builtin_amdgcn_mfma_f32_16x16x32_bf16(a[mt], b[nt], acc[mt][nt], 0, 0, 0);
  }

  // Epilogue. C/D layout: col = lane&15, row = quad*4 + reg
  float lsum = 0.f;
  const bool diag = (ti == tj);
#pragma unroll
  for (int mt = 0; mt < 4; mt++) {
    const int rloc = mt * 16 + quad * 4;
    const int4 rl = *(const int4*)(tg + rowBase + rloc);
    const int rlab[4] = {rl.x, rl.y, rl.z, rl.w};
#pragma unroll
    for (int nt = 0; nt < 4; nt++) {
      const int cloc = nt * 16 + l16;
      const int tc = tg[colBase + cloc];
      const int col = colBase + cloc;
#pragma unroll
      for (int r = 0; r < 4; r++) {
        const float s = acc[mt][nt][r];
        float c = (rlab[r] == tc) ? ((s < 1.f) ? 1.f - s : 0.f)
                                  : ((s > MARGIN) ? s : 0.f);
        float wgt;
        if (!diag) {
          wgt = 2.f;
        } else {
          const int row = rowBase + rloc + r;
          wgt = (row < col) ? 2.f : ((row == col) ? 1.f : 0.f);
        }
        lsum += wgt * c;
      }
    }
  }

#pragma unroll
  for (int off = 32; off > 0; off >>= 1) lsum += __shfl_down(lsum, off, 64);
  if (lane == 0) atomicAdd(out, lsum * (1.0f / NROWS));
}

extern "C" void kernel_launch(void* const* d_in, const int* in_sizes, int n_in,
                              void* d_out, int out_size, void* d_ws, size_t ws_size,
                              hipStream_t stream) {
  const float* x = (const float*)d_in[0];
  const int* tg  = (const int*)d_in[1];
  float* out     = (float*)d_out;
  ushort* xb     = (ushort*)d_ws;   // bf16 X, 8 MiB

  convert_kernel<<<(NROWS * NDIM / 16) / 256, 256, 0, stream>>>(
      (const float4*)x, (shortx8*)xb, out);
  loss_kernel<<<NT, 64, 0, stream>>>(xb, tg, out);
}

// Round 7
// 126.842 us; speedup vs baseline: 1.5918x; 1.5918x over previous
//
#include <hip/hip_runtime.h>
#include <hip/hip_bf16.h>
#include <stdint.h>

#define NROWS 8192
#define NDIM  512
#define MARGIN 0.3f
#define NT    2080     // 64*65/2 upper-triangular 128x128 blocks

typedef __attribute__((ext_vector_type(4))) float floatx4;
typedef __attribute__((ext_vector_type(8))) short shortx8;

__device__ inline unsigned short f32_to_bf16_bits(float x) {
  union { float f; unsigned int u; } v; v.f = x;
  unsigned int r = v.u + 0x7FFFu + ((v.u >> 16) & 1u);  // RNE
  return (unsigned short)(r >> 16);
}

// fp32 -> bf16, one float4 -> ushort4 per thread (16B load / 8B store, coalesced)
__global__ void convert_kernel(const float4* __restrict__ in, ushort4* __restrict__ out,
                               float* __restrict__ loss_out) {
  int i = blockIdx.x * blockDim.x + threadIdx.x;
  if (i == 0) loss_out[0] = 0.f;          // d_out poisoned each replay
  float4 f = in[i];
  ushort4 o;
  o.x = f32_to_bf16_bits(f.x);
  o.y = f32_to_bf16_bits(f.y);
  o.z = f32_to_bf16_bits(f.z);
  o.w = f32_to_bf16_bits(f.w);
  out[i] = o;
}

__device__ inline void gload_lds16(const void* g, void* l) {
  __builtin_amdgcn_global_load_lds(
      (const __attribute__((address_space(1))) unsigned int*)g,
      (__attribute__((address_space(3))) unsigned int*)l, 16, 0, 0);
}

// 128x128 upper-tri blocks of sim = X·X^T, bf16 MFMA, 4 waves (2x2 of 64x64).
// AITER-style K-loop: 3-stage LDS pipeline (BK=32, 48 KB -> 3 blocks/CU),
// prefetch distance 2 iterations, raw `s_barrier` WITHOUT vmcnt(0) drain.
// Ordering: each wave waits `s_waitcnt vmcnt(4)` (its own tile-kt loads done,
// tile-kt+1 still in flight), then s_barrier => ALL waves' tile-kt loads done.
// Label loads are issued before staging so the vmcnt FIFO retires them first.
__launch_bounds__(256, 3)
__global__ void loss_kernel(const ushort* __restrict__ Xb, const int* __restrict__ tg,
                            float* __restrict__ out) {
  __shared__ ushort As[3][4096];   // 128 rows x 32 k, 8 KB per stage
  __shared__ ushort Bs[3][4096];
  __shared__ float red[4];

  // super-tile decode (R4: 8 diagonal supers of 36, then 28 off-diag of 64)
  int t = blockIdx.x;
  int bi, bj;
  if (t < 288) {
    int si = t / 36;
    int q  = t - si * 36;
    int ii = 0;
    while (q >= 8 - ii) { q -= 8 - ii; ii++; }
    bi = si * 8 + ii;
    bj = si * 8 + ii + q;
  } else {
    int q = t - 288;
    int s = q >> 6, r = q & 63;
    int si = 0;
    while (s >= 7 - si) { s -= 7 - si; si++; }
    int sj = si + 1 + s;
    bi = si * 8 + (r >> 3);
    bj = sj * 8 + (r & 7);
  }

  const int tid  = threadIdx.x;
  const int lane = tid & 63;
  const int w    = tid >> 6;
  const int wm   = w >> 1, wn = w & 1;   // 2x2 waves, 64x64 each
  const int quad = lane >> 4;
  const int l16  = lane & 15;

  const int rowBase = bi * 128;
  const int colBase = bj * 128;

  // ---- label preloads (issued FIRST: oldest in vmcnt FIFO) ----
  int4 rl[4];
  int  tc[4];
#pragma unroll
  for (int mt = 0; mt < 4; mt++)
    rl[mt] = *(const int4*)(tg + rowBase + wm * 64 + mt * 16 + quad * 4);
#pragma unroll
  for (int nt = 0; nt < 4; nt++)
    tc[nt] = tg[colBase + wn * 64 + nt * 16 + l16];

  // ---- staging geometry: tile 128x32 = 8 chunks of 1 KB (16 rows each);
  // wave w stages chunks {2w, 2w+1} of A and of B (4 DMA loads per wave/iter).
  // DMA deposits lane's 16B at chunkBase + lane*16: physical slot sp=lane&3
  // holds global 16B-slot sp ^ ((r>>1)&3)  (XOR swizzle, conflict-free reads).
  const int srt = lane >> 2;
  const int sp  = lane & 3;
  unsigned gA[2], gB[2];
#pragma unroll
  for (int c = 0; c < 2; c++) {
    int ch   = w * 2 + c;
    int r_t  = ch * 16 + srt;
    int slot = sp ^ ((r_t >> 1) & 3);
    gA[c] = (unsigned)((rowBase + r_t) * NDIM + slot * 8);
    gB[c] = (unsigned)((colBase + r_t) * NDIM + slot * 8);
  }

#define STAGE(KT, BUF)                                                    \
  do {                                                                    \
    _Pragma("unroll")                                                     \
    for (int c = 0; c < 2; c++) {                                         \
      int ch = w * 2 + c;                                                 \
      gload_lds16(Xb + gA[c] + (KT) * 32, &As[BUF][ch * 512]);            \
      gload_lds16(Xb + gB[c] + (KT) * 32, &Bs[BUF][ch * 512]);            \
    }                                                                     \
  } while (0)

  floatx4 acc[4][4];
#pragma unroll
  for (int a = 0; a < 4; a++)
#pragma unroll
    for (int b = 0; b < 4; b++) acc[a][b] = (floatx4)(0.f);

  STAGE(0, 0);
  STAGE(1, 1);

#pragma unroll
  for (int kt = 0; kt < 16; kt++) {
    const int buf = kt % 3;
    // own tile-kt loads landed (labels + older stages retired first; tile-kt+1
    // 4 loads may stay in flight). Never vmcnt(0) mid-loop.
    if (kt < 15) asm volatile("s_waitcnt vmcnt(4)" ::: "memory");
    else         asm volatile("s_waitcnt vmcnt(0)" ::: "memory");
    asm volatile("s_barrier" ::: "memory");      // raw barrier: NO drain
    if (kt < 14) STAGE(kt + 2, (kt + 2) % 3);    // distance-2 prefetch

    shortx8 a[4], b[4];
#pragma unroll
    for (int mt = 0; mt < 4; mt++) {
      const int row = wm * 64 + mt * 16 + l16;
      const int phys = quad ^ ((row >> 1) & 3);
      a[mt] = *(const shortx8*)(&As[buf][row * 32 + phys * 8]);
    }
#pragma unroll
    for (int nt = 0; nt < 4; nt++) {
      const int row = wn * 64 + nt * 16 + l16;
      const int phys = quad ^ ((row >> 1) & 3);
      b[nt] = *(const shortx8*)(&Bs[buf][row * 32 + phys * 8]);
    }
#pragma unroll
    for (int mt = 0; mt < 4; mt++)
#pragma unroll
      for (int nt = 0; nt < 4; nt++)
        acc[mt][nt] = __builtin_amdgcn_mfma_f32_16x16x32_bf16(a[mt], b[nt], acc[mt][nt], 0, 0, 0);
  }

  // Epilogue. C/D layout: col = lane&15, row = quad*4 + reg
  float lsum = 0.f;
  const bool diag = (bi == bj);
#pragma unroll
  for (int mt = 0; mt < 4; mt++) {
    const int rloc = wm * 64 + mt * 16 + quad * 4;
    const int rlab[4] = {rl[mt].x, rl[mt].y, rl[mt].z, rl[mt].w};
#pragma unroll
    for (int nt = 0; nt < 4; nt++) {
      const int cloc = wn * 64 + nt * 16 + l16;
      const int col = colBase + cloc;
#pragma unroll
      for (int r = 0; r < 4; r++) {
        const float s = acc[mt][nt][r];
        float c = (rlab[r] == tc[nt]) ? ((s < 1.f) ? 1.f - s : 0.f)
                                      : ((s > MARGIN) ? s : 0.f);
        float wgt;
        if (!diag) {
          wgt = 2.f;
        } else {
          const int row = rowBase + rloc + r;
          wgt = (row < col) ? 2.f : ((row == col) ? 1.f : 0.f);
        }
        lsum += wgt * c;
      }
    }
  }

#pragma unroll
  for (int off = 32; off > 0; off >>= 1) lsum += __shfl_down(lsum, off, 64);
  if (lane == 0) red[w] = lsum;
  __syncthreads();
  if (tid == 0)
    atomicAdd(out, (red[0] + red[1] + red[2] + red[3]) * (1.0f / NROWS));
}

extern "C" void kernel_launch(void* const* d_in, const int* in_sizes, int n_in,
                              void* d_out, int out_size, void* d_ws, size_t ws_size,
                              hipStream_t stream) {
  const float* x = (const float*)d_in[0];
  const int* tg  = (const int*)d_in[1];
  float* out     = (float*)d_out;
  ushort* xb     = (ushort*)d_ws;   // bf16 X, 8 MiB

  convert_kernel<<<(NROWS * NDIM / 4) / 256, 256, 0, stream>>>(
      (const float4*)x, (ushort4*)xb, out);
  loss_kernel<<<NT, 256, 0, stream>>>(xb, tg, out);
}